// Round 6
// baseline (709.423 us; speedup 1.0000x reference)
//
#include <hip/hip_runtime.h>
#include <hip/hip_bf16.h>

// Problem constants (fixed by the reference)
#define NN 150000      // nodes
#define EE 600000      // edges
#define F_IN 32        // input node features
#define HD 128         // hidden dim
#define GG 2048        // graphs
#define CAP 28         // max degree bucket capacity (Poisson(4): P(deg>=28) ~ 4e-18)
#define NP 150016      // NN rounded up to 64-node blocks

typedef __attribute__((ext_vector_type(8))) short bf16x8;
typedef __attribute__((ext_vector_type(4))) float f32x4;

__device__ inline void split_bf16(float v, unsigned short& hi, unsigned short& lo) {
    __hip_bfloat16 h = __float2bfloat16(v);
    float hv = __bfloat162float(h);
    __hip_bfloat16 l = __float2bfloat16(v - hv);
    hi = *reinterpret_cast<unsigned short*>(&h);
    lo = *reinterpret_cast<unsigned short*>(&l);
}
__device__ inline unsigned short bf16_hi(float v) {
    __hip_bfloat16 h = __float2bfloat16(v);
    return *reinterpret_cast<unsigned short*>(&h);
}
__device__ inline unsigned short bf16_lo(float v) {
    __hip_bfloat16 h = __float2bfloat16(v);
    float hv = __bfloat162float(h);
    __hip_bfloat16 l = __float2bfloat16(v - hv);
    return *reinterpret_cast<unsigned short*>(&l);
}

// ---------------------------------------------------------------------------
// Zero-init for workspace regions
// ---------------------------------------------------------------------------
__global__ void init_zero(int* __restrict__ cnt_node, int* __restrict__ cntg,
                          float* __restrict__ pooled) {
    int i = blockIdx.x * blockDim.x + threadIdx.x;
    if (i < NN) cnt_node[i] = 0;
    if (i < GG) cntg[i] = 0;
    if (i < GG * HD) pooled[i] = 0.f;
}

// ---------------------------------------------------------------------------
// CSR-bucket build + per-graph node counts (fused)
// ---------------------------------------------------------------------------
__global__ void build_graph(const int* __restrict__ ei, const int* __restrict__ batch,
                            int* __restrict__ cnt_node, int* __restrict__ cntg,
                            int* __restrict__ bucket) {
    int e = blockIdx.x * blockDim.x + threadIdx.x;
    if (e < NN) atomicAdd(&cntg[batch[e]], 1);
    if (e >= EE) return;
    int src = ei[e];         // edge_index[0]
    int dst = ei[EE + e];    // edge_index[1]
    int slot = atomicAdd(&cnt_node[dst], 1);
    if (slot < CAP) bucket[dst * CAP + slot] = src;
}

// ---------------------------------------------------------------------------
// Weight prep: fp32 W[K][H] -> split-bf16 packed in LANE-LINEAR fragment order:
//   pidx = ((nt*KS + ks)*64 + lane)*8 + e,  lane = quad*16 + m,
//   holds WT[nt*16+m][ks*32+quad*8+e] = W[ks*32+quad*8+e][nt*16+m].
// One wave B-frag load = one contiguous 1 KB read.
// ---------------------------------------------------------------------------
struct PrepDesc { const float* src; unsigned short* dhi; unsigned short* dlo; int K; };
struct PrepArgs { PrepDesc d[9]; };

__global__ void prep_weights(PrepArgs pa) {
    PrepDesc de = pa.d[blockIdx.y];
    int total = de.K * HD;
    int KS = de.K >> 5;
    for (int idx = blockIdx.x * blockDim.x + threadIdx.x; idx < total;
         idx += gridDim.x * blockDim.x) {
        int k = idx / HD, h = idx - (idx / HD) * HD;   // src is [K][H]
        unsigned short hi, lo;
        split_bf16(de.src[idx], hi, lo);
        int nt = h >> 4, m = h & 15;
        int ks = k >> 5, quad = (k >> 3) & 3, e = k & 7;
        int lane = quad * 16 + m;
        int pidx = ((nt * KS + ks) * 64 + lane) * 8 + e;
        de.dhi[pidx] = hi;
        de.dlo[pidx] = lo;
    }
}

// ---------------------------------------------------------------------------
// Fused GIN layer: gather-aggregate (fp32, registers) + 3-layer MLP on the
// matrix pipe, split-bf16 (hi+lo): D = Ah*Bh + Al*Bh + Ah*Bl (lo*lo dropped).
//
// Wave tile: 16 nodes x 128 out features (M=16: per-wave reg footprint ~half
// of the M=32 variant -> occupancy is the gather-concurrency lever). Block =
// 4 waves = 64 nodes; LDS 17.4 KB/block. Epilogue restages the fp32 output
// tile through LDS (two 8-row half passes) and stores full 512B rows
// coalesced -> no partial-line RMW traffic.
// ---------------------------------------------------------------------------
template <int K_IN>
__launch_bounds__(256, 4)
__global__ void gin_layer(const float* __restrict__ hin,
                          const int* __restrict__ cnt_node,
                          const int* __restrict__ bucket,
                          const unsigned short* __restrict__ w1h, const unsigned short* __restrict__ w1l,
                          const float* __restrict__ b1,
                          const unsigned short* __restrict__ w2h, const unsigned short* __restrict__ w2l,
                          const float* __restrict__ b2,
                          const unsigned short* __restrict__ w3h, const unsigned short* __restrict__ w3l,
                          const float* __restrict__ b3,
                          float* __restrict__ out) {
    constexpr int KS1 = K_IN / 32;
    __shared__ unsigned short sh[4][16][HD + 8];   // 17408 B / block

    const int wave = threadIdx.x >> 6;
    const int lane = threadIdx.x & 63;
    const int m = lane & 15;      // node row / out-feature sub-col
    const int quad = lane >> 4;   // 0..3
    const int nodeBase = blockIdx.x * 64 + wave * 16;

    // ---- fused aggregation: self + neighbors, fp32 -> split-bf16 A frags ----
    int node = nodeBase + m;
    node = node < NN ? node : NN - 1;
    int cnt = cnt_node[node];
    cnt = cnt < CAP ? cnt : CAP;
    const int* b = bucket + (size_t)node * CAP;
    const float* rowSelf = hin + (size_t)node * K_IN + quad * 8;
    float4 a0[KS1], a1[KS1];
#pragma unroll
    for (int ks = 0; ks < KS1; ks++) {
        a0[ks] = *(const float4*)(rowSelf + ks * 32);
        a1[ks] = *(const float4*)(rowSelf + ks * 32 + 4);
    }
    int i = 0;
    for (; i + 2 <= cnt; i += 2) {
        const float* rA = hin + (size_t)b[i] * K_IN + quad * 8;
        const float* rB = hin + (size_t)b[i + 1] * K_IN + quad * 8;
        float4 vA0[KS1], vA1[KS1], vB0[KS1], vB1[KS1];
#pragma unroll
        for (int ks = 0; ks < KS1; ks++) {
            vA0[ks] = *(const float4*)(rA + ks * 32);
            vA1[ks] = *(const float4*)(rA + ks * 32 + 4);
            vB0[ks] = *(const float4*)(rB + ks * 32);
            vB1[ks] = *(const float4*)(rB + ks * 32 + 4);
        }
#pragma unroll
        for (int ks = 0; ks < KS1; ks++) {
            a0[ks].x += vA0[ks].x + vB0[ks].x;
            a0[ks].y += vA0[ks].y + vB0[ks].y;
            a0[ks].z += vA0[ks].z + vB0[ks].z;
            a0[ks].w += vA0[ks].w + vB0[ks].w;
            a1[ks].x += vA1[ks].x + vB1[ks].x;
            a1[ks].y += vA1[ks].y + vB1[ks].y;
            a1[ks].z += vA1[ks].z + vB1[ks].z;
            a1[ks].w += vA1[ks].w + vB1[ks].w;
        }
    }
    if (i < cnt) {
        const float* rA = hin + (size_t)b[i] * K_IN + quad * 8;
#pragma unroll
        for (int ks = 0; ks < KS1; ks++) {
            float4 v0 = *(const float4*)(rA + ks * 32);
            float4 v1 = *(const float4*)(rA + ks * 32 + 4);
            a0[ks].x += v0.x; a0[ks].y += v0.y; a0[ks].z += v0.z; a0[ks].w += v0.w;
            a1[ks].x += v1.x; a1[ks].y += v1.y; a1[ks].z += v1.z; a1[ks].w += v1.w;
        }
    }
    bf16x8 ah[KS1], al[KS1];
#pragma unroll
    for (int ks = 0; ks < KS1; ks++) {
        float t[8] = {a0[ks].x, a0[ks].y, a0[ks].z, a0[ks].w,
                      a1[ks].x, a1[ks].y, a1[ks].z, a1[ks].w};
        bf16x8 vh, vl;
#pragma unroll
        for (int e = 0; e < 8; e++) {
            unsigned short hi, lo;
            split_bf16(t[e], hi, lo);
            vh[e] = (short)hi;
            vl[e] = (short)lo;
        }
        ah[ks] = vh;
        al[ks] = vl;
    }

    f32x4 acc[8];

    // ---- stage 1 ----
#pragma unroll
    for (int nt = 0; nt < 8; nt++) {
        bf16x8 bh[KS1], bl[KS1];
#pragma unroll
        for (int ks = 0; ks < KS1; ks++) {
            bh[ks] = *(const bf16x8*)(w1h + ((nt * KS1 + ks) * 64 + lane) * 8);
            bl[ks] = *(const bf16x8*)(w1l + ((nt * KS1 + ks) * 64 + lane) * 8);
        }
        f32x4 c = {0.f, 0.f, 0.f, 0.f};
#pragma unroll
        for (int ks = 0; ks < KS1; ks++) {
            c = __builtin_amdgcn_mfma_f32_16x16x32_bf16(ah[ks], bh[ks], c, 0, 0, 0);
            c = __builtin_amdgcn_mfma_f32_16x16x32_bf16(al[ks], bh[ks], c, 0, 0, 0);
            c = __builtin_amdgcn_mfma_f32_16x16x32_bf16(ah[ks], bl[ks], c, 0, 0, 0);
        }
        acc[nt] = c;
    }

    // ---- transpose 1->2 through LDS: hi pass then lo pass ----
    bf16x8 a2h[4], a2l[4];
#pragma unroll
    for (int nt = 0; nt < 8; nt++) {
        float bj = b1[nt * 16 + m];
#pragma unroll
        for (int r = 0; r < 4; r++)
            sh[wave][quad * 4 + r][nt * 16 + m] = bf16_hi(fmaxf(acc[nt][r] + bj, 0.f));
    }
#pragma unroll
    for (int ks = 0; ks < 4; ks++)
        a2h[ks] = *(const bf16x8*)&sh[wave][m][ks * 32 + quad * 8];
#pragma unroll
    for (int nt = 0; nt < 8; nt++) {
        float bj = b1[nt * 16 + m];
#pragma unroll
        for (int r = 0; r < 4; r++)
            sh[wave][quad * 4 + r][nt * 16 + m] = bf16_lo(fmaxf(acc[nt][r] + bj, 0.f));
    }
#pragma unroll
    for (int ks = 0; ks < 4; ks++)
        a2l[ks] = *(const bf16x8*)&sh[wave][m][ks * 32 + quad * 8];

    // ---- stage 2 ----
#pragma unroll
    for (int nt = 0; nt < 8; nt++) {
        bf16x8 bh[4], bl[4];
#pragma unroll
        for (int ks = 0; ks < 4; ks++) {
            bh[ks] = *(const bf16x8*)(w2h + ((nt * 4 + ks) * 64 + lane) * 8);
            bl[ks] = *(const bf16x8*)(w2l + ((nt * 4 + ks) * 64 + lane) * 8);
        }
        f32x4 c = {0.f, 0.f, 0.f, 0.f};
#pragma unroll
        for (int ks = 0; ks < 4; ks++) {
            c = __builtin_amdgcn_mfma_f32_16x16x32_bf16(a2h[ks], bh[ks], c, 0, 0, 0);
            c = __builtin_amdgcn_mfma_f32_16x16x32_bf16(a2l[ks], bh[ks], c, 0, 0, 0);
            c = __builtin_amdgcn_mfma_f32_16x16x32_bf16(a2h[ks], bl[ks], c, 0, 0, 0);
        }
        acc[nt] = c;
    }

    // ---- transpose 2->3 ----
#pragma unroll
    for (int nt = 0; nt < 8; nt++) {
        float bj = b2[nt * 16 + m];
#pragma unroll
        for (int r = 0; r < 4; r++)
            sh[wave][quad * 4 + r][nt * 16 + m] = bf16_hi(fmaxf(acc[nt][r] + bj, 0.f));
    }
#pragma unroll
    for (int ks = 0; ks < 4; ks++)
        a2h[ks] = *(const bf16x8*)&sh[wave][m][ks * 32 + quad * 8];
#pragma unroll
    for (int nt = 0; nt < 8; nt++) {
        float bj = b2[nt * 16 + m];
#pragma unroll
        for (int r = 0; r < 4; r++)
            sh[wave][quad * 4 + r][nt * 16 + m] = bf16_lo(fmaxf(acc[nt][r] + bj, 0.f));
    }
#pragma unroll
    for (int ks = 0; ks < 4; ks++)
        a2l[ks] = *(const bf16x8*)&sh[wave][m][ks * 32 + quad * 8];

    // ---- stage 3 ----
#pragma unroll
    for (int nt = 0; nt < 8; nt++) {
        bf16x8 bh[4], bl[4];
#pragma unroll
        for (int ks = 0; ks < 4; ks++) {
            bh[ks] = *(const bf16x8*)(w3h + ((nt * 4 + ks) * 64 + lane) * 8);
            bl[ks] = *(const bf16x8*)(w3l + ((nt * 4 + ks) * 64 + lane) * 8);
        }
        f32x4 c = {0.f, 0.f, 0.f, 0.f};
#pragma unroll
        for (int ks = 0; ks < 4; ks++) {
            c = __builtin_amdgcn_mfma_f32_16x16x32_bf16(a2h[ks], bh[ks], c, 0, 0, 0);
            c = __builtin_amdgcn_mfma_f32_16x16x32_bf16(a2l[ks], bh[ks], c, 0, 0, 0);
            c = __builtin_amdgcn_mfma_f32_16x16x32_bf16(a2h[ks], bl[ks], c, 0, 0, 0);
        }
        acc[nt] = c;
    }

    // ---- epilogue: fp32 restage through LDS, coalesced 512B row stores ----
    // Two half passes of 8 rows each; per-wave region (4352 B) holds
    // [8][HD+4] floats (4224 B). Row stride 132 dwords -> 2-way bank
    // aliasing on write (free), minor on read.
    float* shf = (float*)&sh[wave][0][0];
#pragma unroll
    for (int h = 0; h < 2; h++) {
        if ((quad >> 1) == h) {
            int rbase = quad * 4 - 8 * h;   // 0 or 4 within the half
#pragma unroll
            for (int nt = 0; nt < 8; nt++) {
                float bj = b3[nt * 16 + m];
#pragma unroll
                for (int r = 0; r < 4; r++)
                    shf[(rbase + r) * (HD + 4) + nt * 16 + m] =
                        fmaxf(acc[nt][r] + bj, 0.f);
            }
        }
#pragma unroll
        for (int io = 0; io < 4; io++) {
            int row8 = io * 2 + (lane >> 5);          // 0..7
            int col = (lane & 31) * 4;
            int n2 = nodeBase + 8 * h + row8;
            float4 v = *(const float4*)&shf[row8 * (HD + 4) + col];
            if (n2 < NN) *(float4*)&out[(size_t)n2 * HD + col] = v;
        }
    }
}

// ---------------------------------------------------------------------------
// Global mean pool (sum stage): 8 row-slots x 32 float4-lane groups.
// batch is sorted -> run-length accumulate per slot, flush on transition.
// ---------------------------------------------------------------------------
__launch_bounds__(256)
__global__ void pool_sum(const float* __restrict__ h, const int* __restrict__ batch,
                         float* __restrict__ pooled) {
    const int NPB = 256;
    int slot = threadIdx.x >> 5;           // 0..7
    int fg = (threadIdx.x & 31) * 4;       // feature group (float4)
    int n0 = blockIdx.x * NPB + slot;
    int n1 = blockIdx.x * NPB + NPB < NN ? blockIdx.x * NPB + NPB : NN;
    float4 acc = {0.f, 0.f, 0.f, 0.f};
    int gprev = -1;
    for (int n = n0; n < n1; n += 8) {
        int g = batch[n];
        if (g != gprev) {
            if (gprev >= 0) {
                atomicAdd(&pooled[(size_t)gprev * HD + fg + 0], acc.x);
                atomicAdd(&pooled[(size_t)gprev * HD + fg + 1], acc.y);
                atomicAdd(&pooled[(size_t)gprev * HD + fg + 2], acc.z);
                atomicAdd(&pooled[(size_t)gprev * HD + fg + 3], acc.w);
            }
            acc = {0.f, 0.f, 0.f, 0.f};
            gprev = g;
        }
        float4 v = *(const float4*)&h[(size_t)n * HD + fg];
        acc.x += v.x; acc.y += v.y; acc.z += v.z; acc.w += v.w;
    }
    if (gprev >= 0) {
        atomicAdd(&pooled[(size_t)gprev * HD + fg + 0], acc.x);
        atomicAdd(&pooled[(size_t)gprev * HD + fg + 1], acc.y);
        atomicAdd(&pooled[(size_t)gprev * HD + fg + 2], acc.z);
        atomicAdd(&pooled[(size_t)gprev * HD + fg + 3], acc.w);
    }
}

// ---------------------------------------------------------------------------
// Classifier head: one block (128 threads) per graph.
// ---------------------------------------------------------------------------
__launch_bounds__(128)
__global__ void head(const float* __restrict__ pooled, const int* __restrict__ cntg,
                     const float* __restrict__ fc0_w, const float* __restrict__ fc0_b,
                     const float* __restrict__ fc1_w, const float* __restrict__ fc1_b,
                     const float* __restrict__ out_w, const float* __restrict__ out_b,
                     float* __restrict__ out) {
    int g = blockIdx.x;
    int j = threadIdx.x;
    __shared__ float s0[HD];
    __shared__ float s1[HD];
    int c = cntg[g];
    float cf = (float)(c > 1 ? c : 1);
    s0[j] = pooled[(size_t)g * HD + j] / cf;
    __syncthreads();

    float acc = fc0_b[j];
    for (int k = 0; k < HD; k += 4) {
        float4 hv = *(const float4*)&s0[k];
        acc = fmaf(hv.x, fc0_w[(k + 0) * HD + j], acc);
        acc = fmaf(hv.y, fc0_w[(k + 1) * HD + j], acc);
        acc = fmaf(hv.z, fc0_w[(k + 2) * HD + j], acc);
        acc = fmaf(hv.w, fc0_w[(k + 3) * HD + j], acc);
    }
    s1[j] = fmaxf(acc, 0.0f);
    __syncthreads();

    acc = fc1_b[j];
    for (int k = 0; k < HD; k += 4) {
        float4 hv = *(const float4*)&s1[k];
        acc = fmaf(hv.x, fc1_w[(k + 0) * HD + j], acc);
        acc = fmaf(hv.y, fc1_w[(k + 1) * HD + j], acc);
        acc = fmaf(hv.z, fc1_w[(k + 2) * HD + j], acc);
        acc = fmaf(hv.w, fc1_w[(k + 3) * HD + j], acc);
    }
    float v = fmaxf(acc, 0.0f);

    float p0 = v * out_w[j * 2 + 0];
    float p1 = v * out_w[j * 2 + 1];
    __syncthreads();
    s0[j] = p0;
    s1[j] = p1;
    __syncthreads();
    for (int off = 64; off >= 1; off >>= 1) {
        if (j < off) {
            s0[j] += s0[j + off];
            s1[j] += s1[j + off];
        }
        __syncthreads();
    }
    if (j == 0) {
        out[(size_t)g * 2 + 0] = s0[0] + out_b[0];
        out[(size_t)g * 2 + 1] = s1[0] + out_b[1];
    }
}

// ---------------------------------------------------------------------------
extern "C" void kernel_launch(void* const* d_in, const int* in_sizes, int n_in,
                              void* d_out, int out_size, void* d_ws, size_t ws_size,
                              hipStream_t stream) {
    const float* x     = (const float*)d_in[0];
    const int*   ei    = (const int*)d_in[1];
    const int*   batch = (const int*)d_in[2];
    const float* cw[3][6];
    for (int i = 0; i < 3; i++)
        for (int k = 0; k < 6; k++) cw[i][k] = (const float*)d_in[3 + 6 * i + k];
    const float* fc0_w = (const float*)d_in[21];
    const float* fc0_b = (const float*)d_in[22];
    const float* fc1_w = (const float*)d_in[23];
    const float* fc1_b = (const float*)d_in[24];
    const float* out_w = (const float*)d_in[25];
    const float* out_b = (const float*)d_in[26];
    float* out = (float*)d_out;

    char* ws = (char*)d_ws;
    size_t off = 0;
    auto carve = [&](size_t bytes) {
        void* p = ws + off;
        off += (bytes + 255) & ~(size_t)255;
        return p;
    };
    int*   cnt_node = (int*)carve((size_t)NN * 4);
    int*   cntg     = (int*)carve((size_t)GG * 4);
    float* pooled   = (float*)carve((size_t)GG * HD * 4);
    int*   bucket   = (int*)carve((size_t)NN * CAP * 4);
    float* hA       = (float*)carve((size_t)NP * HD * 4);
    float* hB       = (float*)carve((size_t)NP * HD * 4);
    unsigned short* wHi[9];
    unsigned short* wLo[9];
    int wK[9] = {F_IN, HD, HD, HD, HD, HD, HD, HD, HD};
    for (int i = 0; i < 9; i++) {
        wHi[i] = (unsigned short*)carve((size_t)wK[i] * HD * 2);
        wLo[i] = (unsigned short*)carve((size_t)wK[i] * HD * 2);
    }
    (void)ws_size;

    init_zero<<<(GG * HD + 255) / 256, 256, 0, stream>>>(cnt_node, cntg, pooled);
    build_graph<<<(EE + 255) / 256, 256, 0, stream>>>(ei, batch, cnt_node, cntg, bucket);

    PrepArgs pa;
    for (int l = 0; l < 3; l++)
        for (int s = 0; s < 3; s++) {
            int i = l * 3 + s;
            pa.d[i].src = cw[l][2 * s];
            pa.d[i].dhi = wHi[i];
            pa.d[i].dlo = wLo[i];
            pa.d[i].K = wK[i];
        }
    prep_weights<<<dim3(16, 9), 256, 0, stream>>>(pa);

    const int blocks = NP / 64;  // 2344

    // ---- GIN layer 0 (K=32): x -> hA ----
    gin_layer<F_IN><<<blocks, 256, 0, stream>>>(x, cnt_node, bucket,
        wHi[0], wLo[0], cw[0][1], wHi[1], wLo[1], cw[0][3], wHi[2], wLo[2], cw[0][5], hA);
    // ---- GIN layer 1: hA -> hB ----
    gin_layer<HD><<<blocks, 256, 0, stream>>>(hA, cnt_node, bucket,
        wHi[3], wLo[3], cw[1][1], wHi[4], wLo[4], cw[1][3], wHi[5], wLo[5], cw[1][5], hB);
    // ---- GIN layer 2: hB -> hA ----
    gin_layer<HD><<<blocks, 256, 0, stream>>>(hB, cnt_node, bucket,
        wHi[6], wLo[6], cw[2][1], wHi[7], wLo[7], cw[2][3], wHi[8], wLo[8], cw[2][5], hA);

    // ---- pooling + head ----
    pool_sum<<<(NN + 255) / 256, 256, 0, stream>>>(hA, batch, pooled);
    head<<<GG, 128, 0, stream>>>(pooled, cntg, fc0_w, fc0_b, fc1_w, fc1_b, out_w, out_b, out);
}

// Round 8
// 650.919 us; speedup vs baseline: 1.0899x; 1.0899x over previous
//
#include <hip/hip_runtime.h>
#include <hip/hip_bf16.h>

// Problem constants (fixed by the reference)
#define NN 150000      // nodes
#define EE 600000      // edges
#define F_IN 32        // input node features
#define HD 128         // hidden dim
#define GG 2048        // graphs
#define CAP 28         // max degree bucket capacity (Poisson(4): P(deg>=28) ~ 4e-18)
#define NP 150016      // NN rounded up to 128-node blocks: 1172*128

typedef __attribute__((ext_vector_type(8))) short bf16x8;
typedef __attribute__((ext_vector_type(4))) float f32x4;

__device__ inline void split_bf16(float v, unsigned short& hi, unsigned short& lo) {
    __hip_bfloat16 h = __float2bfloat16(v);
    float hv = __bfloat162float(h);
    __hip_bfloat16 l = __float2bfloat16(v - hv);
    hi = *reinterpret_cast<unsigned short*>(&h);
    lo = *reinterpret_cast<unsigned short*>(&l);
}
__device__ inline unsigned short bf16_hi(float v) {
    __hip_bfloat16 h = __float2bfloat16(v);
    return *reinterpret_cast<unsigned short*>(&h);
}
__device__ inline unsigned short bf16_lo(float v) {
    __hip_bfloat16 h = __float2bfloat16(v);
    float hv = __bfloat162float(h);
    __hip_bfloat16 l = __float2bfloat16(v - hv);
    return *reinterpret_cast<unsigned short*>(&l);
}

// ---------------------------------------------------------------------------
// Zero-init for workspace regions
// ---------------------------------------------------------------------------
__global__ void init_zero(int* __restrict__ cnt_node, int* __restrict__ cntg,
                          float* __restrict__ pooled) {
    int i = blockIdx.x * blockDim.x + threadIdx.x;
    if (i < NN) cnt_node[i] = 0;
    if (i < GG) cntg[i] = 0;
    if (i < GG * HD) pooled[i] = 0.f;
}

// ---------------------------------------------------------------------------
// CSR-bucket build + per-graph node counts (fused)
// ---------------------------------------------------------------------------
__global__ void build_graph(const int* __restrict__ ei, const int* __restrict__ batch,
                            int* __restrict__ cnt_node, int* __restrict__ cntg,
                            int* __restrict__ bucket) {
    int e = blockIdx.x * blockDim.x + threadIdx.x;
    if (e < NN) atomicAdd(&cntg[batch[e]], 1);
    if (e >= EE) return;
    int src = ei[e];         // edge_index[0]
    int dst = ei[EE + e];    // edge_index[1]
    int slot = atomicAdd(&cnt_node[dst], 1);
    if (slot < CAP) bucket[dst * CAP + slot] = src;
}

// ---------------------------------------------------------------------------
// Weight prep: fp32 W[K][H] -> split-bf16 packed in LANE-LINEAR fragment order:
//   pidx = ((nt*KS + ks)*64 + lane)*8 + e,  lane = quad*16 + m,
//   holds WT[nt*16+m][ks*32+quad*8+e] = W[ks*32+quad*8+e][nt*16+m].
// One wave B-frag load = one contiguous 1 KB read.
// ---------------------------------------------------------------------------
struct PrepDesc { const float* src; unsigned short* dhi; unsigned short* dlo; int K; };
struct PrepArgs { PrepDesc d[9]; };

__global__ void prep_weights(PrepArgs pa) {
    PrepDesc de = pa.d[blockIdx.y];
    int total = de.K * HD;
    int KS = de.K >> 5;
    for (int idx = blockIdx.x * blockDim.x + threadIdx.x; idx < total;
         idx += gridDim.x * blockDim.x) {
        int k = idx / HD, h = idx - (idx / HD) * HD;   // src is [K][H]
        unsigned short hi, lo;
        split_bf16(de.src[idx], hi, lo);
        int nt = h >> 4, m = h & 15;
        int ks = k >> 5, quad = (k >> 3) & 3, e = k & 7;
        int lane = quad * 16 + m;
        int pidx = ((nt * KS + ks) * 64 + lane) * 8 + e;
        de.dhi[pidx] = hi;
        de.dlo[pidx] = lo;
    }
}

// ---------------------------------------------------------------------------
// Fused GIN layer: gather-aggregate (fp32, registers) + 3-layer MLP on the
// matrix pipe, split-bf16 (hi+lo): D = Ah*Bh + Al*Bh + Ah*Bl (lo*lo dropped).
//
// Wave tile: 32 nodes (2x16) x 128 features — R5 config: enough VGPRs
// (launch_bounds(256,3)) to keep the 2-row-unrolled gather's 16 float4
// loads in flight (R6's (256,4)/M=16 showed VGPR=64 serializes the gather:
// BW fell 2.05->1.43 TB/s despite higher occupancy).
// Epilogue: fp32 restage through LDS -> coalesced full-row nontemporal
// stores (write-once output bypasses L3, keeping gather rows resident).
// ---------------------------------------------------------------------------
template <int K_IN>
__launch_bounds__(256, 3)
__global__ void gin_layer(const float* __restrict__ hin,
                          const int* __restrict__ cnt_node,
                          const int* __restrict__ bucket,
                          const unsigned short* __restrict__ w1h, const unsigned short* __restrict__ w1l,
                          const float* __restrict__ b1,
                          const unsigned short* __restrict__ w2h, const unsigned short* __restrict__ w2l,
                          const float* __restrict__ b2,
                          const unsigned short* __restrict__ w3h, const unsigned short* __restrict__ w3l,
                          const float* __restrict__ b3,
                          float* __restrict__ out) {
    constexpr int KS1 = K_IN / 32;
    __shared__ unsigned short sh[4][32][HD + 8];   // 34816 B / block

    const int wave = threadIdx.x >> 6;
    const int lane = threadIdx.x & 63;
    const int m = lane & 15;      // node row within a 16-set / out-feature col
    const int quad = lane >> 4;   // 0..3
    const int nodeBase = blockIdx.x * 128 + wave * 32;

    // ---- fused aggregation: self + neighbors, fp32 -> split-bf16 A frags ----
    bf16x8 ah[2][KS1], al[2][KS1];
#pragma unroll
    for (int s = 0; s < 2; s++) {
        int node = nodeBase + s * 16 + m;
        node = node < NN ? node : NN - 1;
        const float* rowSelf = hin + (size_t)node * K_IN + quad * 8;
        float4 a0[KS1], a1[KS1];
#pragma unroll
        for (int ks = 0; ks < KS1; ks++) {
            a0[ks] = *(const float4*)(rowSelf + ks * 32);
            a1[ks] = *(const float4*)(rowSelf + ks * 32 + 4);
        }
        int cnt = cnt_node[node];
        cnt = cnt < CAP ? cnt : CAP;
        const int* b = bucket + (size_t)node * CAP;
        int i = 0;
        for (; i + 2 <= cnt; i += 2) {
            const float* rA = hin + (size_t)b[i] * K_IN + quad * 8;
            const float* rB = hin + (size_t)b[i + 1] * K_IN + quad * 8;
            float4 vA0[KS1], vA1[KS1], vB0[KS1], vB1[KS1];
#pragma unroll
            for (int ks = 0; ks < KS1; ks++) {
                vA0[ks] = *(const float4*)(rA + ks * 32);
                vA1[ks] = *(const float4*)(rA + ks * 32 + 4);
                vB0[ks] = *(const float4*)(rB + ks * 32);
                vB1[ks] = *(const float4*)(rB + ks * 32 + 4);
            }
#pragma unroll
            for (int ks = 0; ks < KS1; ks++) {
                a0[ks].x += vA0[ks].x + vB0[ks].x;
                a0[ks].y += vA0[ks].y + vB0[ks].y;
                a0[ks].z += vA0[ks].z + vB0[ks].z;
                a0[ks].w += vA0[ks].w + vB0[ks].w;
                a1[ks].x += vA1[ks].x + vB1[ks].x;
                a1[ks].y += vA1[ks].y + vB1[ks].y;
                a1[ks].z += vA1[ks].z + vB1[ks].z;
                a1[ks].w += vA1[ks].w + vB1[ks].w;
            }
        }
        if (i < cnt) {
            const float* rA = hin + (size_t)b[i] * K_IN + quad * 8;
#pragma unroll
            for (int ks = 0; ks < KS1; ks++) {
                float4 v0 = *(const float4*)(rA + ks * 32);
                float4 v1 = *(const float4*)(rA + ks * 32 + 4);
                a0[ks].x += v0.x; a0[ks].y += v0.y; a0[ks].z += v0.z; a0[ks].w += v0.w;
                a1[ks].x += v1.x; a1[ks].y += v1.y; a1[ks].z += v1.z; a1[ks].w += v1.w;
            }
        }
#pragma unroll
        for (int ks = 0; ks < KS1; ks++) {
            float t[8] = {a0[ks].x, a0[ks].y, a0[ks].z, a0[ks].w,
                          a1[ks].x, a1[ks].y, a1[ks].z, a1[ks].w};
            bf16x8 vh, vl;
#pragma unroll
            for (int e = 0; e < 8; e++) {
                unsigned short hi, lo;
                split_bf16(t[e], hi, lo);
                vh[e] = (short)hi;
                vl[e] = (short)lo;
            }
            ah[s][ks] = vh;
            al[s][ks] = vl;
        }
    }

    f32x4 acc[2][8];

    // ---- stage 1 ----
#pragma unroll
    for (int nt = 0; nt < 8; nt++) {
        bf16x8 bh[KS1], bl[KS1];
#pragma unroll
        for (int ks = 0; ks < KS1; ks++) {
            bh[ks] = *(const bf16x8*)(w1h + ((nt * KS1 + ks) * 64 + lane) * 8);
            bl[ks] = *(const bf16x8*)(w1l + ((nt * KS1 + ks) * 64 + lane) * 8);
        }
        f32x4 c0 = {0.f, 0.f, 0.f, 0.f};
        f32x4 c1 = {0.f, 0.f, 0.f, 0.f};
#pragma unroll
        for (int ks = 0; ks < KS1; ks++) {
            c0 = __builtin_amdgcn_mfma_f32_16x16x32_bf16(ah[0][ks], bh[ks], c0, 0, 0, 0);
            c1 = __builtin_amdgcn_mfma_f32_16x16x32_bf16(ah[1][ks], bh[ks], c1, 0, 0, 0);
            c0 = __builtin_amdgcn_mfma_f32_16x16x32_bf16(al[0][ks], bh[ks], c0, 0, 0, 0);
            c1 = __builtin_amdgcn_mfma_f32_16x16x32_bf16(al[1][ks], bh[ks], c1, 0, 0, 0);
            c0 = __builtin_amdgcn_mfma_f32_16x16x32_bf16(ah[0][ks], bl[ks], c0, 0, 0, 0);
            c1 = __builtin_amdgcn_mfma_f32_16x16x32_bf16(ah[1][ks], bl[ks], c1, 0, 0, 0);
        }
        acc[0][nt] = c0;
        acc[1][nt] = c1;
    }

    // ---- transpose 1->2 through single LDS buffer: hi pass then lo pass ----
    bf16x8 a2h[2][4], a2l[2][4];
#pragma unroll
    for (int s = 0; s < 2; s++)
#pragma unroll
        for (int nt = 0; nt < 8; nt++) {
            float bj = b1[nt * 16 + m];
#pragma unroll
            for (int r = 0; r < 4; r++)
                sh[wave][s * 16 + quad * 4 + r][nt * 16 + m] =
                    bf16_hi(fmaxf(acc[s][nt][r] + bj, 0.f));
        }
#pragma unroll
    for (int s = 0; s < 2; s++)
#pragma unroll
        for (int ks = 0; ks < 4; ks++)
            a2h[s][ks] = *(const bf16x8*)&sh[wave][s * 16 + m][ks * 32 + quad * 8];
#pragma unroll
    for (int s = 0; s < 2; s++)
#pragma unroll
        for (int nt = 0; nt < 8; nt++) {
            float bj = b1[nt * 16 + m];
#pragma unroll
            for (int r = 0; r < 4; r++)
                sh[wave][s * 16 + quad * 4 + r][nt * 16 + m] =
                    bf16_lo(fmaxf(acc[s][nt][r] + bj, 0.f));
        }
#pragma unroll
    for (int s = 0; s < 2; s++)
#pragma unroll
        for (int ks = 0; ks < 4; ks++)
            a2l[s][ks] = *(const bf16x8*)&sh[wave][s * 16 + m][ks * 32 + quad * 8];

    // ---- stage 2 ----
#pragma unroll
    for (int nt = 0; nt < 8; nt++) {
        bf16x8 bh[4], bl[4];
#pragma unroll
        for (int ks = 0; ks < 4; ks++) {
            bh[ks] = *(const bf16x8*)(w2h + ((nt * 4 + ks) * 64 + lane) * 8);
            bl[ks] = *(const bf16x8*)(w2l + ((nt * 4 + ks) * 64 + lane) * 8);
        }
        f32x4 c0 = {0.f, 0.f, 0.f, 0.f};
        f32x4 c1 = {0.f, 0.f, 0.f, 0.f};
#pragma unroll
        for (int ks = 0; ks < 4; ks++) {
            c0 = __builtin_amdgcn_mfma_f32_16x16x32_bf16(a2h[0][ks], bh[ks], c0, 0, 0, 0);
            c1 = __builtin_amdgcn_mfma_f32_16x16x32_bf16(a2h[1][ks], bh[ks], c1, 0, 0, 0);
            c0 = __builtin_amdgcn_mfma_f32_16x16x32_bf16(a2l[0][ks], bh[ks], c0, 0, 0, 0);
            c1 = __builtin_amdgcn_mfma_f32_16x16x32_bf16(a2l[1][ks], bh[ks], c1, 0, 0, 0);
            c0 = __builtin_amdgcn_mfma_f32_16x16x32_bf16(a2h[0][ks], bl[ks], c0, 0, 0, 0);
            c1 = __builtin_amdgcn_mfma_f32_16x16x32_bf16(a2h[1][ks], bl[ks], c1, 0, 0, 0);
        }
        acc[0][nt] = c0;
        acc[1][nt] = c1;
    }

    // ---- transpose 2->3 ----
#pragma unroll
    for (int s = 0; s < 2; s++)
#pragma unroll
        for (int nt = 0; nt < 8; nt++) {
            float bj = b2[nt * 16 + m];
#pragma unroll
            for (int r = 0; r < 4; r++)
                sh[wave][s * 16 + quad * 4 + r][nt * 16 + m] =
                    bf16_hi(fmaxf(acc[s][nt][r] + bj, 0.f));
        }
#pragma unroll
    for (int s = 0; s < 2; s++)
#pragma unroll
        for (int ks = 0; ks < 4; ks++)
            a2h[s][ks] = *(const bf16x8*)&sh[wave][s * 16 + m][ks * 32 + quad * 8];
#pragma unroll
    for (int s = 0; s < 2; s++)
#pragma unroll
        for (int nt = 0; nt < 8; nt++) {
            float bj = b2[nt * 16 + m];
#pragma unroll
            for (int r = 0; r < 4; r++)
                sh[wave][s * 16 + quad * 4 + r][nt * 16 + m] =
                    bf16_lo(fmaxf(acc[s][nt][r] + bj, 0.f));
        }
#pragma unroll
    for (int s = 0; s < 2; s++)
#pragma unroll
        for (int ks = 0; ks < 4; ks++)
            a2l[s][ks] = *(const bf16x8*)&sh[wave][s * 16 + m][ks * 32 + quad * 8];

    // ---- stage 3 ----
#pragma unroll
    for (int nt = 0; nt < 8; nt++) {
        bf16x8 bh[4], bl[4];
#pragma unroll
        for (int ks = 0; ks < 4; ks++) {
            bh[ks] = *(const bf16x8*)(w3h + ((nt * 4 + ks) * 64 + lane) * 8);
            bl[ks] = *(const bf16x8*)(w3l + ((nt * 4 + ks) * 64 + lane) * 8);
        }
        f32x4 c0 = {0.f, 0.f, 0.f, 0.f};
        f32x4 c1 = {0.f, 0.f, 0.f, 0.f};
#pragma unroll
        for (int ks = 0; ks < 4; ks++) {
            c0 = __builtin_amdgcn_mfma_f32_16x16x32_bf16(a2h[0][ks], bh[ks], c0, 0, 0, 0);
            c1 = __builtin_amdgcn_mfma_f32_16x16x32_bf16(a2h[1][ks], bh[ks], c1, 0, 0, 0);
            c0 = __builtin_amdgcn_mfma_f32_16x16x32_bf16(a2l[0][ks], bh[ks], c0, 0, 0, 0);
            c1 = __builtin_amdgcn_mfma_f32_16x16x32_bf16(a2l[1][ks], bh[ks], c1, 0, 0, 0);
            c0 = __builtin_amdgcn_mfma_f32_16x16x32_bf16(a2h[0][ks], bl[ks], c0, 0, 0, 0);
            c1 = __builtin_amdgcn_mfma_f32_16x16x32_bf16(a2h[1][ks], bl[ks], c1, 0, 0, 0);
        }
        acc[0][nt] = c0;
        acc[1][nt] = c1;
    }

    // ---- epilogue: fp32 restage through LDS, coalesced 512B nontemporal ----
    // Per-wave LDS region = 32*136 ushorts = 2176 floats; each half-pass
    // stages 16 rows x stride 132 (2112 floats). Stores: 2 full rows per
    // instruction (32 lanes x f32x4), write-once -> nontemporal (bypass L3).
    float* shf = (float*)&sh[wave][0][0];
#pragma unroll
    for (int h = 0; h < 2; h++) {
#pragma unroll
        for (int nt = 0; nt < 8; nt++) {
            float bj = b3[nt * 16 + m];
#pragma unroll
            for (int r = 0; r < 4; r++)
                shf[(quad * 4 + r) * 132 + nt * 16 + m] =
                    fmaxf(acc[h][nt][r] + bj, 0.f);
        }
#pragma unroll
        for (int io = 0; io < 8; io++) {
            int row16 = io * 2 + (lane >> 5);         // 0..15
            int col = (lane & 31) * 4;
            int n2 = nodeBase + h * 16 + row16;
            f32x4 v = *(const f32x4*)&shf[row16 * 132 + col];
            if (n2 < NN)
                __builtin_nontemporal_store(v, (f32x4*)&out[(size_t)n2 * HD + col]);
        }
    }
}

// ---------------------------------------------------------------------------
// Global mean pool (sum stage): 8 row-slots x 32 float4-lane groups.
// batch is sorted -> run-length accumulate per slot, flush on transition.
// ---------------------------------------------------------------------------
__launch_bounds__(256)
__global__ void pool_sum(const float* __restrict__ h, const int* __restrict__ batch,
                         float* __restrict__ pooled) {
    const int NPB = 256;
    int slot = threadIdx.x >> 5;           // 0..7
    int fg = (threadIdx.x & 31) * 4;       // feature group (float4)
    int n0 = blockIdx.x * NPB + slot;
    int n1 = blockIdx.x * NPB + NPB < NN ? blockIdx.x * NPB + NPB : NN;
    float4 acc = {0.f, 0.f, 0.f, 0.f};
    int gprev = -1;
    for (int n = n0; n < n1; n += 8) {
        int g = batch[n];
        if (g != gprev) {
            if (gprev >= 0) {
                atomicAdd(&pooled[(size_t)gprev * HD + fg + 0], acc.x);
                atomicAdd(&pooled[(size_t)gprev * HD + fg + 1], acc.y);
                atomicAdd(&pooled[(size_t)gprev * HD + fg + 2], acc.z);
                atomicAdd(&pooled[(size_t)gprev * HD + fg + 3], acc.w);
            }
            acc = {0.f, 0.f, 0.f, 0.f};
            gprev = g;
        }
        float4 v = *(const float4*)&h[(size_t)n * HD + fg];
        acc.x += v.x; acc.y += v.y; acc.z += v.z; acc.w += v.w;
    }
    if (gprev >= 0) {
        atomicAdd(&pooled[(size_t)gprev * HD + fg + 0], acc.x);
        atomicAdd(&pooled[(size_t)gprev * HD + fg + 1], acc.y);
        atomicAdd(&pooled[(size_t)gprev * HD + fg + 2], acc.z);
        atomicAdd(&pooled[(size_t)gprev * HD + fg + 3], acc.w);
    }
}

// ---------------------------------------------------------------------------
// Classifier head: one block (128 threads) per graph.
// ---------------------------------------------------------------------------
__launch_bounds__(128)
__global__ void head(const float* __restrict__ pooled, const int* __restrict__ cntg,
                     const float* __restrict__ fc0_w, const float* __restrict__ fc0_b,
                     const float* __restrict__ fc1_w, const float* __restrict__ fc1_b,
                     const float* __restrict__ out_w, const float* __restrict__ out_b,
                     float* __restrict__ out) {
    int g = blockIdx.x;
    int j = threadIdx.x;
    __shared__ float s0[HD];
    __shared__ float s1[HD];
    int c = cntg[g];
    float cf = (float)(c > 1 ? c : 1);
    s0[j] = pooled[(size_t)g * HD + j] / cf;
    __syncthreads();

    float acc = fc0_b[j];
    for (int k = 0; k < HD; k += 4) {
        float4 hv = *(const float4*)&s0[k];
        acc = fmaf(hv.x, fc0_w[(k + 0) * HD + j], acc);
        acc = fmaf(hv.y, fc0_w[(k + 1) * HD + j], acc);
        acc = fmaf(hv.z, fc0_w[(k + 2) * HD + j], acc);
        acc = fmaf(hv.w, fc0_w[(k + 3) * HD + j], acc);
    }
    s1[j] = fmaxf(acc, 0.0f);
    __syncthreads();

    acc = fc1_b[j];
    for (int k = 0; k < HD; k += 4) {
        float4 hv = *(const float4*)&s1[k];
        acc = fmaf(hv.x, fc1_w[(k + 0) * HD + j], acc);
        acc = fmaf(hv.y, fc1_w[(k + 1) * HD + j], acc);
        acc = fmaf(hv.z, fc1_w[(k + 2) * HD + j], acc);
        acc = fmaf(hv.w, fc1_w[(k + 3) * HD + j], acc);
    }
    float v = fmaxf(acc, 0.0f);

    float p0 = v * out_w[j * 2 + 0];
    float p1 = v * out_w[j * 2 + 1];
    __syncthreads();
    s0[j] = p0;
    s1[j] = p1;
    __syncthreads();
    for (int off = 64; off >= 1; off >>= 1) {
        if (j < off) {
            s0[j] += s0[j + off];
            s1[j] += s1[j + off];
        }
        __syncthreads();
    }
    if (j == 0) {
        out[(size_t)g * 2 + 0] = s0[0] + out_b[0];
        out[(size_t)g * 2 + 1] = s1[0] + out_b[1];
    }
}

// ---------------------------------------------------------------------------
extern "C" void kernel_launch(void* const* d_in, const int* in_sizes, int n_in,
                              void* d_out, int out_size, void* d_ws, size_t ws_size,
                              hipStream_t stream) {
    const float* x     = (const float*)d_in[0];
    const int*   ei    = (const int*)d_in[1];
    const int*   batch = (const int*)d_in[2];
    const float* cw[3][6];
    for (int i = 0; i < 3; i++)
        for (int k = 0; k < 6; k++) cw[i][k] = (const float*)d_in[3 + 6 * i + k];
    const float* fc0_w = (const float*)d_in[21];
    const float* fc0_b = (const float*)d_in[22];
    const float* fc1_w = (const float*)d_in[23];
    const float* fc1_b = (const float*)d_in[24];
    const float* out_w = (const float*)d_in[25];
    const float* out_b = (const float*)d_in[26];
    float* out = (float*)d_out;

    char* ws = (char*)d_ws;
    size_t off = 0;
    auto carve = [&](size_t bytes) {
        void* p = ws + off;
        off += (bytes + 255) & ~(size_t)255;
        return p;
    };
    int*   cnt_node = (int*)carve((size_t)NN * 4);
    int*   cntg     = (int*)carve((size_t)GG * 4);
    float* pooled   = (float*)carve((size_t)GG * HD * 4);
    int*   bucket   = (int*)carve((size_t)NN * CAP * 4);
    float* hA       = (float*)carve((size_t)NP * HD * 4);
    float* hB       = (float*)carve((size_t)NP * HD * 4);
    unsigned short* wHi[9];
    unsigned short* wLo[9];
    int wK[9] = {F_IN, HD, HD, HD, HD, HD, HD, HD, HD};
    for (int i = 0; i < 9; i++) {
        wHi[i] = (unsigned short*)carve((size_t)wK[i] * HD * 2);
        wLo[i] = (unsigned short*)carve((size_t)wK[i] * HD * 2);
    }
    (void)ws_size;

    init_zero<<<(GG * HD + 255) / 256, 256, 0, stream>>>(cnt_node, cntg, pooled);
    build_graph<<<(EE + 255) / 256, 256, 0, stream>>>(ei, batch, cnt_node, cntg, bucket);

    PrepArgs pa;
    for (int l = 0; l < 3; l++)
        for (int s = 0; s < 3; s++) {
            int i = l * 3 + s;
            pa.d[i].src = cw[l][2 * s];
            pa.d[i].dhi = wHi[i];
            pa.d[i].dlo = wLo[i];
            pa.d[i].K = wK[i];
        }
    prep_weights<<<dim3(16, 9), 256, 0, stream>>>(pa);

    const int blocks = NP / 128;  // 1172

    // ---- GIN layer 0 (K=32): x -> hA ----
    gin_layer<F_IN><<<blocks, 256, 0, stream>>>(x, cnt_node, bucket,
        wHi[0], wLo[0], cw[0][1], wHi[1], wLo[1], cw[0][3], wHi[2], wLo[2], cw[0][5], hA);
    // ---- GIN layer 1: hA -> hB ----
    gin_layer<HD><<<blocks, 256, 0, stream>>>(hA, cnt_node, bucket,
        wHi[3], wLo[3], cw[1][1], wHi[4], wLo[4], cw[1][3], wHi[5], wLo[5], cw[1][5], hB);
    // ---- GIN layer 2: hB -> hA ----
    gin_layer<HD><<<blocks, 256, 0, stream>>>(hB, cnt_node, bucket,
        wHi[6], wLo[6], cw[2][1], wHi[7], wLo[7], cw[2][3], wHi[8], wLo[8], cw[2][5], hA);

    // ---- pooling + head ----
    pool_sum<<<(NN + 255) / 256, 256, 0, stream>>>(hA, batch, pooled);
    head<<<GG, 128, 0, stream>>>(pooled, cntg, fc0_w, fc0_b, fc1_w, fc1_b, out_w, out_b, out);
}

// Round 9
// 628.161 us; speedup vs baseline: 1.1294x; 1.0362x over previous
//
#include <hip/hip_runtime.h>
#include <hip/hip_bf16.h>

// Problem constants (fixed by the reference)
#define NN 150000      // nodes
#define EE 600000      // edges
#define F_IN 32        // input node features
#define HD 128         // hidden dim
#define GG 2048        // graphs
#define CAP 28         // max degree bucket capacity (Poisson(4): P(deg>=28) ~ 4e-18)
#define NP 150016      // NN rounded up to 128-node blocks: 1172*128

typedef __attribute__((ext_vector_type(8))) short bf16x8;
typedef __attribute__((ext_vector_type(4))) float f32x4;

__device__ inline void split_bf16(float v, unsigned short& hi, unsigned short& lo) {
    __hip_bfloat16 h = __float2bfloat16(v);
    float hv = __bfloat162float(h);
    __hip_bfloat16 l = __float2bfloat16(v - hv);
    hi = *reinterpret_cast<unsigned short*>(&h);
    lo = *reinterpret_cast<unsigned short*>(&l);
}
__device__ inline unsigned short bf16_hi(float v) {
    __hip_bfloat16 h = __float2bfloat16(v);
    return *reinterpret_cast<unsigned short*>(&h);
}
__device__ inline unsigned short bf16_lo(float v) {
    __hip_bfloat16 h = __float2bfloat16(v);
    float hv = __bfloat162float(h);
    __hip_bfloat16 l = __float2bfloat16(v - hv);
    return *reinterpret_cast<unsigned short*>(&l);
}

// ---------------------------------------------------------------------------
// Zero-init for workspace regions
// ---------------------------------------------------------------------------
__global__ void init_zero(int* __restrict__ cnt_node, int* __restrict__ cntg,
                          float* __restrict__ pooled) {
    int i = blockIdx.x * blockDim.x + threadIdx.x;
    if (i < NN) cnt_node[i] = 0;
    if (i < GG) cntg[i] = 0;
    if (i < GG * HD) pooled[i] = 0.f;
}

// ---------------------------------------------------------------------------
// CSR-bucket build + per-graph node counts (fused)
// ---------------------------------------------------------------------------
__global__ void build_graph(const int* __restrict__ ei, const int* __restrict__ batch,
                            int* __restrict__ cnt_node, int* __restrict__ cntg,
                            int* __restrict__ bucket) {
    int e = blockIdx.x * blockDim.x + threadIdx.x;
    if (e < NN) atomicAdd(&cntg[batch[e]], 1);
    if (e >= EE) return;
    int src = ei[e];         // edge_index[0]
    int dst = ei[EE + e];    // edge_index[1]
    int slot = atomicAdd(&cnt_node[dst], 1);
    if (slot < CAP) bucket[dst * CAP + slot] = src;
}

// ---------------------------------------------------------------------------
// Weight prep: fp32 W[K][H] -> split-bf16 packed in LANE-LINEAR fragment order:
//   pidx = ((nt*KS + ks)*64 + lane)*8 + e,  lane = quad*16 + m,
//   holds WT[nt*16+m][ks*32+quad*8+e] = W[ks*32+quad*8+e][nt*16+m].
// One wave B-frag load = one contiguous 1 KB read.
// ---------------------------------------------------------------------------
struct PrepDesc { const float* src; unsigned short* dhi; unsigned short* dlo; int K; };
struct PrepArgs { PrepDesc d[9]; };

__global__ void prep_weights(PrepArgs pa) {
    PrepDesc de = pa.d[blockIdx.y];
    int total = de.K * HD;
    int KS = de.K >> 5;
    for (int idx = blockIdx.x * blockDim.x + threadIdx.x; idx < total;
         idx += gridDim.x * blockDim.x) {
        int k = idx / HD, h = idx - (idx / HD) * HD;   // src is [K][H]
        unsigned short hi, lo;
        split_bf16(de.src[idx], hi, lo);
        int nt = h >> 4, m = h & 15;
        int ks = k >> 5, quad = (k >> 3) & 3, e = k & 7;
        int lane = quad * 16 + m;
        int pidx = ((nt * KS + ks) * 64 + lane) * 8 + e;
        de.dhi[pidx] = hi;
        de.dlo[pidx] = lo;
    }
}

// ---------------------------------------------------------------------------
// Fused GIN layer: gather-aggregate (fp32, registers) + 3-layer MLP on the
// matrix pipe, split-bf16 (hi+lo): D = Ah*Bh + Al*Bh + Ah*Bl (lo*lo dropped).
//
// Wave tile: 32 nodes (2x16) x 128 features; launch_bounds(256,3) keeps the
// 2-row-unrolled gather's 16 float4 loads in flight (R6's M=16/VGPR=64
// config serialized the gather). Plain cached stores — the output is the
// next layer's gather input (R8 showed nontemporal stores cost +8 MB FETCH
// +20 MB WRITE). POOL=true (last layer): skip the global write entirely and
// run-length atomicAdd per-graph sums into pooled[] (deletes 75 MB write +
// 77 MB pool re-read + the pool_sum dispatch).
// ---------------------------------------------------------------------------
template <int K_IN, bool POOL>
__launch_bounds__(256, 3)
__global__ void gin_layer(const float* __restrict__ hin,
                          const int* __restrict__ cnt_node,
                          const int* __restrict__ bucket,
                          const unsigned short* __restrict__ w1h, const unsigned short* __restrict__ w1l,
                          const float* __restrict__ b1,
                          const unsigned short* __restrict__ w2h, const unsigned short* __restrict__ w2l,
                          const float* __restrict__ b2,
                          const unsigned short* __restrict__ w3h, const unsigned short* __restrict__ w3l,
                          const float* __restrict__ b3,
                          float* __restrict__ out,
                          const int* __restrict__ batch,
                          float* __restrict__ pooled) {
    constexpr int KS1 = K_IN / 32;
    __shared__ unsigned short sh[4][32][HD + 8];   // 34816 B / block

    const int wave = threadIdx.x >> 6;
    const int lane = threadIdx.x & 63;
    const int m = lane & 15;      // node row within a 16-set / out-feature col
    const int quad = lane >> 4;   // 0..3
    const int nodeBase = blockIdx.x * 128 + wave * 32;

    // ---- fused aggregation: self + neighbors, fp32 -> split-bf16 A frags ----
    bf16x8 ah[2][KS1], al[2][KS1];
#pragma unroll
    for (int s = 0; s < 2; s++) {
        int node = nodeBase + s * 16 + m;
        node = node < NN ? node : NN - 1;
        const float* rowSelf = hin + (size_t)node * K_IN + quad * 8;
        float4 a0[KS1], a1[KS1];
#pragma unroll
        for (int ks = 0; ks < KS1; ks++) {
            a0[ks] = *(const float4*)(rowSelf + ks * 32);
            a1[ks] = *(const float4*)(rowSelf + ks * 32 + 4);
        }
        int cnt = cnt_node[node];
        cnt = cnt < CAP ? cnt : CAP;
        const int* b = bucket + (size_t)node * CAP;
        int i = 0;
        for (; i + 2 <= cnt; i += 2) {
            const float* rA = hin + (size_t)b[i] * K_IN + quad * 8;
            const float* rB = hin + (size_t)b[i + 1] * K_IN + quad * 8;
            float4 vA0[KS1], vA1[KS1], vB0[KS1], vB1[KS1];
#pragma unroll
            for (int ks = 0; ks < KS1; ks++) {
                vA0[ks] = *(const float4*)(rA + ks * 32);
                vA1[ks] = *(const float4*)(rA + ks * 32 + 4);
                vB0[ks] = *(const float4*)(rB + ks * 32);
                vB1[ks] = *(const float4*)(rB + ks * 32 + 4);
            }
#pragma unroll
            for (int ks = 0; ks < KS1; ks++) {
                a0[ks].x += vA0[ks].x + vB0[ks].x;
                a0[ks].y += vA0[ks].y + vB0[ks].y;
                a0[ks].z += vA0[ks].z + vB0[ks].z;
                a0[ks].w += vA0[ks].w + vB0[ks].w;
                a1[ks].x += vA1[ks].x + vB1[ks].x;
                a1[ks].y += vA1[ks].y + vB1[ks].y;
                a1[ks].z += vA1[ks].z + vB1[ks].z;
                a1[ks].w += vA1[ks].w + vB1[ks].w;
            }
        }
        if (i < cnt) {
            const float* rA = hin + (size_t)b[i] * K_IN + quad * 8;
#pragma unroll
            for (int ks = 0; ks < KS1; ks++) {
                float4 v0 = *(const float4*)(rA + ks * 32);
                float4 v1 = *(const float4*)(rA + ks * 32 + 4);
                a0[ks].x += v0.x; a0[ks].y += v0.y; a0[ks].z += v0.z; a0[ks].w += v0.w;
                a1[ks].x += v1.x; a1[ks].y += v1.y; a1[ks].z += v1.z; a1[ks].w += v1.w;
            }
        }
#pragma unroll
        for (int ks = 0; ks < KS1; ks++) {
            float t[8] = {a0[ks].x, a0[ks].y, a0[ks].z, a0[ks].w,
                          a1[ks].x, a1[ks].y, a1[ks].z, a1[ks].w};
            bf16x8 vh, vl;
#pragma unroll
            for (int e = 0; e < 8; e++) {
                unsigned short hi, lo;
                split_bf16(t[e], hi, lo);
                vh[e] = (short)hi;
                vl[e] = (short)lo;
            }
            ah[s][ks] = vh;
            al[s][ks] = vl;
        }
    }

    f32x4 acc[2][8];

    // ---- stage 1 ----
#pragma unroll
    for (int nt = 0; nt < 8; nt++) {
        bf16x8 bh[KS1], bl[KS1];
#pragma unroll
        for (int ks = 0; ks < KS1; ks++) {
            bh[ks] = *(const bf16x8*)(w1h + ((nt * KS1 + ks) * 64 + lane) * 8);
            bl[ks] = *(const bf16x8*)(w1l + ((nt * KS1 + ks) * 64 + lane) * 8);
        }
        f32x4 c0 = {0.f, 0.f, 0.f, 0.f};
        f32x4 c1 = {0.f, 0.f, 0.f, 0.f};
#pragma unroll
        for (int ks = 0; ks < KS1; ks++) {
            c0 = __builtin_amdgcn_mfma_f32_16x16x32_bf16(ah[0][ks], bh[ks], c0, 0, 0, 0);
            c1 = __builtin_amdgcn_mfma_f32_16x16x32_bf16(ah[1][ks], bh[ks], c1, 0, 0, 0);
            c0 = __builtin_amdgcn_mfma_f32_16x16x32_bf16(al[0][ks], bh[ks], c0, 0, 0, 0);
            c1 = __builtin_amdgcn_mfma_f32_16x16x32_bf16(al[1][ks], bh[ks], c1, 0, 0, 0);
            c0 = __builtin_amdgcn_mfma_f32_16x16x32_bf16(ah[0][ks], bl[ks], c0, 0, 0, 0);
            c1 = __builtin_amdgcn_mfma_f32_16x16x32_bf16(ah[1][ks], bl[ks], c1, 0, 0, 0);
        }
        acc[0][nt] = c0;
        acc[1][nt] = c1;
    }

    // ---- transpose 1->2 through single LDS buffer: hi pass then lo pass ----
    bf16x8 a2h[2][4], a2l[2][4];
#pragma unroll
    for (int s = 0; s < 2; s++)
#pragma unroll
        for (int nt = 0; nt < 8; nt++) {
            float bj = b1[nt * 16 + m];
#pragma unroll
            for (int r = 0; r < 4; r++)
                sh[wave][s * 16 + quad * 4 + r][nt * 16 + m] =
                    bf16_hi(fmaxf(acc[s][nt][r] + bj, 0.f));
        }
#pragma unroll
    for (int s = 0; s < 2; s++)
#pragma unroll
        for (int ks = 0; ks < 4; ks++)
            a2h[s][ks] = *(const bf16x8*)&sh[wave][s * 16 + m][ks * 32 + quad * 8];
#pragma unroll
    for (int s = 0; s < 2; s++)
#pragma unroll
        for (int nt = 0; nt < 8; nt++) {
            float bj = b1[nt * 16 + m];
#pragma unroll
            for (int r = 0; r < 4; r++)
                sh[wave][s * 16 + quad * 4 + r][nt * 16 + m] =
                    bf16_lo(fmaxf(acc[s][nt][r] + bj, 0.f));
        }
#pragma unroll
    for (int s = 0; s < 2; s++)
#pragma unroll
        for (int ks = 0; ks < 4; ks++)
            a2l[s][ks] = *(const bf16x8*)&sh[wave][s * 16 + m][ks * 32 + quad * 8];

    // ---- stage 2 ----
#pragma unroll
    for (int nt = 0; nt < 8; nt++) {
        bf16x8 bh[4], bl[4];
#pragma unroll
        for (int ks = 0; ks < 4; ks++) {
            bh[ks] = *(const bf16x8*)(w2h + ((nt * 4 + ks) * 64 + lane) * 8);
            bl[ks] = *(const bf16x8*)(w2l + ((nt * 4 + ks) * 64 + lane) * 8);
        }
        f32x4 c0 = {0.f, 0.f, 0.f, 0.f};
        f32x4 c1 = {0.f, 0.f, 0.f, 0.f};
#pragma unroll
        for (int ks = 0; ks < 4; ks++) {
            c0 = __builtin_amdgcn_mfma_f32_16x16x32_bf16(a2h[0][ks], bh[ks], c0, 0, 0, 0);
            c1 = __builtin_amdgcn_mfma_f32_16x16x32_bf16(a2h[1][ks], bh[ks], c1, 0, 0, 0);
            c0 = __builtin_amdgcn_mfma_f32_16x16x32_bf16(a2l[0][ks], bh[ks], c0, 0, 0, 0);
            c1 = __builtin_amdgcn_mfma_f32_16x16x32_bf16(a2l[1][ks], bh[ks], c1, 0, 0, 0);
            c0 = __builtin_amdgcn_mfma_f32_16x16x32_bf16(a2h[0][ks], bl[ks], c0, 0, 0, 0);
            c1 = __builtin_amdgcn_mfma_f32_16x16x32_bf16(a2h[1][ks], bl[ks], c1, 0, 0, 0);
        }
        acc[0][nt] = c0;
        acc[1][nt] = c1;
    }

    // ---- transpose 2->3 ----
#pragma unroll
    for (int s = 0; s < 2; s++)
#pragma unroll
        for (int nt = 0; nt < 8; nt++) {
            float bj = b2[nt * 16 + m];
#pragma unroll
            for (int r = 0; r < 4; r++)
                sh[wave][s * 16 + quad * 4 + r][nt * 16 + m] =
                    bf16_hi(fmaxf(acc[s][nt][r] + bj, 0.f));
        }
#pragma unroll
    for (int s = 0; s < 2; s++)
#pragma unroll
        for (int ks = 0; ks < 4; ks++)
            a2h[s][ks] = *(const bf16x8*)&sh[wave][s * 16 + m][ks * 32 + quad * 8];
#pragma unroll
    for (int s = 0; s < 2; s++)
#pragma unroll
        for (int nt = 0; nt < 8; nt++) {
            float bj = b2[nt * 16 + m];
#pragma unroll
            for (int r = 0; r < 4; r++)
                sh[wave][s * 16 + quad * 4 + r][nt * 16 + m] =
                    bf16_lo(fmaxf(acc[s][nt][r] + bj, 0.f));
        }
#pragma unroll
    for (int s = 0; s < 2; s++)
#pragma unroll
        for (int ks = 0; ks < 4; ks++)
            a2l[s][ks] = *(const bf16x8*)&sh[wave][s * 16 + m][ks * 32 + quad * 8];

    // ---- stage 3 ----
#pragma unroll
    for (int nt = 0; nt < 8; nt++) {
        bf16x8 bh[4], bl[4];
#pragma unroll
        for (int ks = 0; ks < 4; ks++) {
            bh[ks] = *(const bf16x8*)(w3h + ((nt * 4 + ks) * 64 + lane) * 8);
            bl[ks] = *(const bf16x8*)(w3l + ((nt * 4 + ks) * 64 + lane) * 8);
        }
        f32x4 c0 = {0.f, 0.f, 0.f, 0.f};
        f32x4 c1 = {0.f, 0.f, 0.f, 0.f};
#pragma unroll
        for (int ks = 0; ks < 4; ks++) {
            c0 = __builtin_amdgcn_mfma_f32_16x16x32_bf16(a2h[0][ks], bh[ks], c0, 0, 0, 0);
            c1 = __builtin_amdgcn_mfma_f32_16x16x32_bf16(a2h[1][ks], bh[ks], c1, 0, 0, 0);
            c0 = __builtin_amdgcn_mfma_f32_16x16x32_bf16(a2l[0][ks], bh[ks], c0, 0, 0, 0);
            c1 = __builtin_amdgcn_mfma_f32_16x16x32_bf16(a2l[1][ks], bh[ks], c1, 0, 0, 0);
            c0 = __builtin_amdgcn_mfma_f32_16x16x32_bf16(a2h[0][ks], bl[ks], c0, 0, 0, 0);
            c1 = __builtin_amdgcn_mfma_f32_16x16x32_bf16(a2h[1][ks], bl[ks], c1, 0, 0, 0);
        }
        acc[0][nt] = c0;
        acc[1][nt] = c1;
    }

    if (POOL) {
        // ---- fused mean-pool (sum) epilogue: no global activation write ----
        // Each lane owns rows s*16+quad*4+r (4 consecutive nodes per s-set,
        // usually one graph at ~73 nodes/graph) x cols nt*16+m. Run-length
        // merge over r, then fp32 atomicAdd into the 1 MB L2-resident pooled.
#pragma unroll
        for (int s = 0; s < 2; s++) {
            int n0 = nodeBase + s * 16 + quad * 4;
            int g0 = batch[min(n0 + 0, NN - 1)];
            int g1 = batch[min(n0 + 1, NN - 1)];
            int g2 = batch[min(n0 + 2, NN - 1)];
            int g3 = batch[min(n0 + 3, NN - 1)];
            bool v0 = n0 + 0 < NN, v1 = n0 + 1 < NN, v2 = n0 + 2 < NN, v3 = n0 + 3 < NN;
#pragma unroll
            for (int nt = 0; nt < 8; nt++) {
                float bj = b3[nt * 16 + m];
                int col = nt * 16 + m;
                float w0 = v0 ? fmaxf(acc[s][nt][0] + bj, 0.f) : 0.f;
                float w1 = v1 ? fmaxf(acc[s][nt][1] + bj, 0.f) : 0.f;
                float w2 = v2 ? fmaxf(acc[s][nt][2] + bj, 0.f) : 0.f;
                float w3 = v3 ? fmaxf(acc[s][nt][3] + bj, 0.f) : 0.f;
                float run = w0;
                int gp = g0;
                if (g1 == gp) run += w1;
                else { atomicAdd(&pooled[(size_t)gp * HD + col], run); run = w1; gp = g1; }
                if (g2 == gp) run += w2;
                else { atomicAdd(&pooled[(size_t)gp * HD + col], run); run = w2; gp = g2; }
                if (g3 == gp) run += w3;
                else { atomicAdd(&pooled[(size_t)gp * HD + col], run); run = w3; gp = g3; }
                atomicAdd(&pooled[(size_t)gp * HD + col], run);
            }
        }
    } else {
        // ---- epilogue: fp32 restage through LDS, coalesced 512B stores ----
        float* shf = (float*)&sh[wave][0][0];
#pragma unroll
        for (int h = 0; h < 2; h++) {
#pragma unroll
            for (int nt = 0; nt < 8; nt++) {
                float bj = b3[nt * 16 + m];
#pragma unroll
                for (int r = 0; r < 4; r++)
                    shf[(quad * 4 + r) * 132 + nt * 16 + m] =
                        fmaxf(acc[h][nt][r] + bj, 0.f);
            }
#pragma unroll
            for (int io = 0; io < 8; io++) {
                int row16 = io * 2 + (lane >> 5);         // 0..15
                int col = (lane & 31) * 4;
                int n2 = nodeBase + h * 16 + row16;
                f32x4 v = *(const f32x4*)&shf[row16 * 132 + col];
                if (n2 < NN) *(f32x4*)&out[(size_t)n2 * HD + col] = v;
            }
        }
    }
}

// ---------------------------------------------------------------------------
// Classifier head: one block (128 threads) per graph.
// ---------------------------------------------------------------------------
__launch_bounds__(128)
__global__ void head(const float* __restrict__ pooled, const int* __restrict__ cntg,
                     const float* __restrict__ fc0_w, const float* __restrict__ fc0_b,
                     const float* __restrict__ fc1_w, const float* __restrict__ fc1_b,
                     const float* __restrict__ out_w, const float* __restrict__ out_b,
                     float* __restrict__ out) {
    int g = blockIdx.x;
    int j = threadIdx.x;
    __shared__ float s0[HD];
    __shared__ float s1[HD];
    int c = cntg[g];
    float cf = (float)(c > 1 ? c : 1);
    s0[j] = pooled[(size_t)g * HD + j] / cf;
    __syncthreads();

    float acc = fc0_b[j];
    for (int k = 0; k < HD; k += 4) {
        float4 hv = *(const float4*)&s0[k];
        acc = fmaf(hv.x, fc0_w[(k + 0) * HD + j], acc);
        acc = fmaf(hv.y, fc0_w[(k + 1) * HD + j], acc);
        acc = fmaf(hv.z, fc0_w[(k + 2) * HD + j], acc);
        acc = fmaf(hv.w, fc0_w[(k + 3) * HD + j], acc);
    }
    s1[j] = fmaxf(acc, 0.0f);
    __syncthreads();

    acc = fc1_b[j];
    for (int k = 0; k < HD; k += 4) {
        float4 hv = *(const float4*)&s1[k];
        acc = fmaf(hv.x, fc1_w[(k + 0) * HD + j], acc);
        acc = fmaf(hv.y, fc1_w[(k + 1) * HD + j], acc);
        acc = fmaf(hv.z, fc1_w[(k + 2) * HD + j], acc);
        acc = fmaf(hv.w, fc1_w[(k + 3) * HD + j], acc);
    }
    float v = fmaxf(acc, 0.0f);

    float p0 = v * out_w[j * 2 + 0];
    float p1 = v * out_w[j * 2 + 1];
    __syncthreads();
    s0[j] = p0;
    s1[j] = p1;
    __syncthreads();
    for (int off = 64; off >= 1; off >>= 1) {
        if (j < off) {
            s0[j] += s0[j + off];
            s1[j] += s1[j + off];
        }
        __syncthreads();
    }
    if (j == 0) {
        out[(size_t)g * 2 + 0] = s0[0] + out_b[0];
        out[(size_t)g * 2 + 1] = s1[0] + out_b[1];
    }
}

// ---------------------------------------------------------------------------
extern "C" void kernel_launch(void* const* d_in, const int* in_sizes, int n_in,
                              void* d_out, int out_size, void* d_ws, size_t ws_size,
                              hipStream_t stream) {
    const float* x     = (const float*)d_in[0];
    const int*   ei    = (const int*)d_in[1];
    const int*   batch = (const int*)d_in[2];
    const float* cw[3][6];
    for (int i = 0; i < 3; i++)
        for (int k = 0; k < 6; k++) cw[i][k] = (const float*)d_in[3 + 6 * i + k];
    const float* fc0_w = (const float*)d_in[21];
    const float* fc0_b = (const float*)d_in[22];
    const float* fc1_w = (const float*)d_in[23];
    const float* fc1_b = (const float*)d_in[24];
    const float* out_w = (const float*)d_in[25];
    const float* out_b = (const float*)d_in[26];
    float* out = (float*)d_out;

    char* ws = (char*)d_ws;
    size_t off = 0;
    auto carve = [&](size_t bytes) {
        void* p = ws + off;
        off += (bytes + 255) & ~(size_t)255;
        return p;
    };
    int*   cnt_node = (int*)carve((size_t)NN * 4);
    int*   cntg     = (int*)carve((size_t)GG * 4);
    float* pooled   = (float*)carve((size_t)GG * HD * 4);
    int*   bucket   = (int*)carve((size_t)NN * CAP * 4);
    float* hA       = (float*)carve((size_t)NP * HD * 4);
    float* hB       = (float*)carve((size_t)NP * HD * 4);
    unsigned short* wHi[9];
    unsigned short* wLo[9];
    int wK[9] = {F_IN, HD, HD, HD, HD, HD, HD, HD, HD};
    for (int i = 0; i < 9; i++) {
        wHi[i] = (unsigned short*)carve((size_t)wK[i] * HD * 2);
        wLo[i] = (unsigned short*)carve((size_t)wK[i] * HD * 2);
    }
    (void)ws_size;

    init_zero<<<(GG * HD + 255) / 256, 256, 0, stream>>>(cnt_node, cntg, pooled);
    build_graph<<<(EE + 255) / 256, 256, 0, stream>>>(ei, batch, cnt_node, cntg, bucket);

    PrepArgs pa;
    for (int l = 0; l < 3; l++)
        for (int s = 0; s < 3; s++) {
            int i = l * 3 + s;
            pa.d[i].src = cw[l][2 * s];
            pa.d[i].dhi = wHi[i];
            pa.d[i].dlo = wLo[i];
            pa.d[i].K = wK[i];
        }
    prep_weights<<<dim3(16, 9), 256, 0, stream>>>(pa);

    const int blocks = NP / 128;  // 1172

    // ---- GIN layer 0 (K=32): x -> hA ----
    gin_layer<F_IN, false><<<blocks, 256, 0, stream>>>(x, cnt_node, bucket,
        wHi[0], wLo[0], cw[0][1], wHi[1], wLo[1], cw[0][3], wHi[2], wLo[2], cw[0][5],
        hA, batch, pooled);
    // ---- GIN layer 1: hA -> hB ----
    gin_layer<HD, false><<<blocks, 256, 0, stream>>>(hA, cnt_node, bucket,
        wHi[3], wLo[3], cw[1][1], wHi[4], wLo[4], cw[1][3], wHi[5], wLo[5], cw[1][5],
        hB, batch, pooled);
    // ---- GIN layer 2: hB -> pooled (fused mean-pool sum, no activation write) ----
    gin_layer<HD, true><<<blocks, 256, 0, stream>>>(hB, cnt_node, bucket,
        wHi[6], wLo[6], cw[2][1], wHi[7], wLo[7], cw[2][3], wHi[8], wLo[8], cw[2][5],
        nullptr, batch, pooled);

    // ---- head ----
    head<<<GG, 128, 0, stream>>>(pooled, cntg, fc0_w, fc0_b, fc1_w, fc1_b, out_w, out_b, out);
}